// Round 4
// baseline (867.889 us; speedup 1.0000x reference)
//
#include <hip/hip_runtime.h>

#define N_NODES 50000
#define N_ENT   100000
#define N_REL   16
#define DIM     128
#define E_EDGES 600000
#define NQ      8192
#define PATH_DIM 5
#define NK      (N_NODES * N_REL)        /* 800000 (dst,rel) segments */
#define KTOT    (N_REL * DIM + DIM)      /* 2176 = 16 rel slots + self slot */
#define NBLK_SEG (NK / 256)              /* 3125 */

typedef __attribute__((ext_vector_type(8))) short short8;
typedef __attribute__((ext_vector_type(4))) float floatx4;

static __device__ __forceinline__ short f2bf(float x) {
  unsigned u = __builtin_bit_cast(unsigned, x);
  u = (u + 0x7FFFu + ((u >> 16) & 1u)) >> 16;   // RNE
  return (short)u;
}
static __device__ __forceinline__ float bf_lo(unsigned u) {
  return __builtin_bit_cast(float, u << 16);
}
static __device__ __forceinline__ float bf_hi(unsigned u) {
  return __builtin_bit_cast(float, u & 0xffff0000u);
}
static __device__ __forceinline__ unsigned pk2(float a, float b) {
  return (unsigned)(unsigned short)f2bf(a) | ((unsigned)(unsigned short)f2bf(b) << 16);
}

static __device__ __forceinline__ int wave_incl_scan(int x) {
  int lane = threadIdx.x & 63;
  #pragma unroll
  for (int off = 1; off < 64; off <<= 1) {
    int y = __shfl_up(x, off, 64);
    if (lane >= off) x += y;
  }
  return x;
}

// ---------- edge sort by (dst*16 + etype): hist -> scan -> scatter ----------
__global__ void k_hist(const int* __restrict__ ei, const int* __restrict__ et,
                       int* __restrict__ hist) {
  int e = blockIdx.x * 256 + threadIdx.x;
  if (e >= E_EDGES) return;
  int key = ei[E_EDGES + e] * N_REL + et[e];
  atomicAdd(&hist[key], 1);
}

__global__ void k_bsum(const int* __restrict__ hist, int* __restrict__ bsum) {
  int t = threadIdx.x;
  int v = hist[blockIdx.x * 256 + t];
  #pragma unroll
  for (int off = 32; off; off >>= 1) v += __shfl_xor(v, off, 64);
  __shared__ int s4[4];
  if ((t & 63) == 0) s4[t >> 6] = v;
  __syncthreads();
  if (t == 0) bsum[blockIdx.x] = s4[0] + s4[1] + s4[2] + s4[3];
}

__global__ void k_bscan(int* __restrict__ bsum) {   // 1 block, 1024 threads, 3125 items
  int t = threadIdx.x;
  int v[4], loc[4], s = 0;
  #pragma unroll
  for (int i = 0; i < 4; i++) {
    int idx = t * 4 + i;
    v[i] = (idx < NBLK_SEG) ? bsum[idx] : 0;
    loc[i] = s; s += v[i];
  }
  int incl = wave_incl_scan(s);
  __shared__ int wsum[16];
  int wid = t >> 6, lane = t & 63;
  if (lane == 63) wsum[wid] = incl;
  __syncthreads();
  if (t < 16) {
    int x = wsum[t];
    #pragma unroll
    for (int off = 1; off < 16; off <<= 1) {
      int y = __shfl_up(x, off, 64);
      if (t >= off) x += y;
    }
    wsum[t] = x;
  }
  __syncthreads();
  int wexcl = wid ? wsum[wid - 1] : 0;
  int texcl = wexcl + incl - s;
  #pragma unroll
  for (int i = 0; i < 4; i++) {
    int idx = t * 4 + i;
    if (idx < NBLK_SEG) bsum[idx] = texcl + loc[i];
  }
}

__global__ void k_offsets(const int* __restrict__ hist, const int* __restrict__ bsum,
                          int* __restrict__ offs, int* __restrict__ cursor) {
  int t = threadIdx.x;
  int g = blockIdx.x * 256 + t;
  int v = hist[g];
  int incl = wave_incl_scan(v);
  __shared__ int wsum[4];
  int wid = t >> 6, lane = t & 63;
  if (lane == 63) wsum[wid] = incl;
  __syncthreads();
  int wexcl = 0;
  for (int i = 0; i < wid; i++) wexcl += wsum[i];
  int off = bsum[blockIdx.x] + wexcl + incl - v;
  offs[g] = off;
  cursor[g] = off;
  if (g == NK - 1) offs[NK] = off + v;
}

__global__ void k_scatter(const int* __restrict__ ei, const int* __restrict__ et,
                          int* __restrict__ cursor, int* __restrict__ ssrc) {
  int e = blockIdx.x * 256 + threadIdx.x;
  if (e >= E_EDGES) return;
  int src = ei[e];
  int key = ei[E_EDGES + e] * N_REL + et[e];
  int pos = atomicAdd(&cursor[key], 1);
  ssrc[pos] = src;
}

// ---------- h0 gather (fp32 emb -> bf16 h) ----------
__global__ void k_h0(const int* __restrict__ nid, const float* __restrict__ emb,
                     unsigned* __restrict__ h) {
  int g = blockIdx.x * 256 + threadIdx.x;     // over N*32
  int n = g >> 5;
  int q = g & 31;
  float4 v = *(const float4*)(emb + (size_t)nid[n] * DIM + q * 4);
  uint2 pk;
  pk.x = pk2(v.x, v.y);
  pk.y = pk2(v.z, v.w);
  *(uint2*)(h + (size_t)n * 64 + q * 2) = pk;
}

// ---------- W_cat bf16, layout [layer][n=out 128][k=2176 (16 rel slots | self)] ----------
__global__ void k_wcat(const float* __restrict__ wrel, const float* __restrict__ wself,
                       short* __restrict__ wcat) {
  int g = blockIdx.x * 256 + threadIdx.x;
  if (g >= 2 * DIM * KTOT) return;
  int l = g / (DIM * KTOT);
  int rem = g - l * DIM * KTOT;
  int n = rem / KTOT;
  int k = rem - n * KTOT;
  float v;
  if (k < N_REL * DIM) {
    int r = k >> 7, d = k & 127;
    v = wrel[(((size_t)l * N_REL + r) * DIM + d) * DIM + n];
  } else {
    int d = k - N_REL * DIM;
    v = wself[((size_t)l * DIM + d) * DIM + n];
  }
  wcat[g] = f2bf(v);
}

// ---------- fused layer: per-wave mean -> LDS A tile -> MFMA, no barriers ----------
// Block: 256 thr = 4 waves; each wave owns 32 rows. For r = 0..16 (16 rels + self):
//  produce A slice [32][128] bf16 in its private LDS chunk, then 4 MFMA k-steps
//  against B (wcat) read directly from global (L2-resident).
__global__ __launch_bounds__(256) void k_layer(const unsigned* __restrict__ h,
                                               const int* __restrict__ offs,
                                               const int* __restrict__ ssrc,
                                               const short* __restrict__ wb,
                                               unsigned* __restrict__ hout) {
  // proven padded layout: per wave, 4 k-chunks of [32 rows][40 shorts]
  __shared__ short As[4][4][32][40];
  __shared__ int   Soffs[4][513];
  int t = threadIdx.x;
  int w = t >> 6, lane = t & 63;
  int quad = lane >> 4, rA = lane & 15;
  int row0 = blockIdx.x * 128 + w * 32;

  // preload this wave's 513 segment offsets (rows row0..row0+31, r 0..15)
  {
    int base = row0 * N_REL;
    for (int i = lane; i < 513; i += 64) {
      int idx = base + i;
      Soffs[w][i] = (idx <= NK) ? offs[idx] : 0;
    }
  }

  floatx4 acc[2][8];
  #pragma unroll
  for (int a = 0; a < 2; a++)
    #pragma unroll
    for (int b = 0; b < 8; b++) acc[a][b] = (floatx4)0.f;

  int wchunk = lane >> 4;           // which 32-col k-chunk this lane's 2 cols fall in
  int wcol   = (lane * 2) & 31;     // col within chunk

  #pragma unroll 1
  for (int r = 0; r < 17; r++) {
    // ---- produce A slice for this r ----
    if (r < 16) {
      #pragma unroll 2
      for (int i = 0; i < 32; i++) {
        int row = row0 + i;
        float s0 = 0.f, s1 = 0.f;
        int cnt = 0;
        if (row < N_NODES) {
          int start = Soffs[w][i * 16 + r];
          int end   = Soffs[w][i * 16 + r + 1];
          cnt = end - start;
          for (int p = start; p < end; ++p) {
            unsigned u = h[(size_t)ssrc[p] * 64 + lane];
            s0 += bf_lo(u); s1 += bf_hi(u);
          }
        }
        float inv = 1.0f / (float)(cnt > 0 ? cnt : 1);
        *(unsigned*)&As[w][wchunk][i][wcol] = pk2(s0 * inv, s1 * inv);
      }
    } else {
      // self slot: copy own h rows
      #pragma unroll 2
      for (int i = 0; i < 32; i++) {
        int row = row0 + i;
        unsigned u = (row < N_NODES) ? h[(size_t)row * 64 + lane] : 0u;
        *(unsigned*)&As[w][wchunk][i][wcol] = u;
      }
    }
    // ---- MFMA: 4 k-steps over this 128-col slot ----
    const short* wbr = wb + r * 128;
    #pragma unroll
    for (int ks = 0; ks < 4; ks++) {
      short8 a0 = *(const short8*)&As[w][ks][rA][quad * 8];
      short8 a1 = *(const short8*)&As[w][ks][16 + rA][quad * 8];
      #pragma unroll
      for (int nt = 0; nt < 8; nt++) {
        short8 b = *(const short8*)(wbr + (size_t)(nt * 16 + rA) * KTOT + ks * 32 + quad * 8);
        acc[0][nt] = __builtin_amdgcn_mfma_f32_16x16x32_bf16(a0, b, acc[0][nt], 0, 0, 0);
        acc[1][nt] = __builtin_amdgcn_mfma_f32_16x16x32_bf16(a1, b, acc[1][nt], 0, 0, 0);
      }
    }
  }
  // ---- epilogue: relu + bf16 store. C: row=(lane>>4)*4+reg, col=lane&15 ----
  #pragma unroll
  for (int mt = 0; mt < 2; mt++)
    #pragma unroll
    for (int nt = 0; nt < 8; nt++)
      #pragma unroll
      for (int j = 0; j < 4; j++) {
        int row = row0 + mt * 16 + quad * 4 + j;
        int col = nt * 16 + rA;
        if (row < N_NODES) {
          float v = fmaxf(acc[mt][nt][j], 0.f);
          ((short*)hout)[(size_t)row * DIM + col] = f2bf(v);
        }
      }
}

// ---------- scoring (bf16 h) ----------
__global__ void k_score(const unsigned* __restrict__ h, const int* __restrict__ heads,
                        const int* __restrict__ rels, const int* __restrict__ tails,
                        const float* __restrict__ rel_emb, const float* __restrict__ path_feat,
                        const int* __restrict__ task_idx, const float* __restrict__ delta_w,
                        const float* __restrict__ lambda_logit, const float* __restrict__ rule_init,
                        float* __restrict__ out) {
  int q = (blockIdx.x * 256 + threadIdx.x) >> 6;
  int lane = threadIdx.x & 63;
  int hd = heads[q], tl = tails[q], rl = rels[q];
  unsigned ua = h[(size_t)hd * 64 + lane];
  unsigned uc = h[(size_t)tl * 64 + lane];
  float2 r = *(const float2*)(rel_emb + (size_t)rl * DIM + lane * 2);
  float s = bf_lo(ua) * r.x * bf_lo(uc) + bf_hi(ua) * r.y * bf_hi(uc);
  #pragma unroll
  for (int off = 32; off; off >>= 1) s += __shfl_xor(s, off, 64);
  if (lane == 0) {
    int task = task_idx[0];
    float sp = 0.f;
    #pragma unroll
    for (int p = 0; p < PATH_DIM; p++)
      sp += path_feat[q * PATH_DIM + p] *
            (rule_init[task * PATH_DIM + p] + delta_w[task * PATH_DIM + p]);
    float lam = 1.f / (1.f + __expf(-lambda_logit[task]));
    out[q] = lam * s + (1.f - lam) * sp;
  }
}

extern "C" void kernel_launch(void* const* d_in, const int* in_sizes, int n_in,
                              void* d_out, int out_size, void* d_ws, size_t ws_size,
                              hipStream_t stream) {
  const int*   node_ids   = (const int*)d_in[0];
  const int*   edge_index = (const int*)d_in[1];
  const int*   edge_type  = (const int*)d_in[2];
  const int*   heads      = (const int*)d_in[3];
  const int*   rels       = (const int*)d_in[4];
  const int*   tails      = (const int*)d_in[5];
  const float* path_feat  = (const float*)d_in[6];
  const int*   task_idx   = (const int*)d_in[7];
  const float* entity_emb = (const float*)d_in[8];
  const float* rel_emb    = (const float*)d_in[9];
  const float* W_self     = (const float*)d_in[10];
  const float* W_rel      = (const float*)d_in[11];
  const float* delta_w    = (const float*)d_in[12];
  const float* lambda_lg  = (const float*)d_in[13];
  const float* rule_init  = (const float*)d_in[14];

  char* ws = (char*)d_ws;
  size_t off = 0;
  auto alloc = [&](size_t bytes) -> void* {
    void* p = ws + off;
    off = (off + bytes + 255) & ~(size_t)255;
    return p;
  };
  unsigned* h_a    = (unsigned*)alloc((size_t)N_NODES * DIM * 2);
  unsigned* h_b    = (unsigned*)alloc((size_t)N_NODES * DIM * 2);
  short*    wcat   = (short*)alloc((size_t)2 * DIM * KTOT * 2);
  int*      offs   = (int*)alloc((size_t)(NK + 1) * 4);
  int*      ssrc   = (int*)alloc((size_t)E_EDGES * 4);
  int*      hist   = (int*)alloc((size_t)(NK + 1) * 4);
  int*      cursor = (int*)alloc((size_t)NK * 4);
  int*      bsum   = (int*)alloc((size_t)NBLK_SEG * 4);

  hipMemsetAsync(hist, 0, (size_t)(NK + 1) * 4, stream);
  int eb = (E_EDGES + 255) / 256;
  k_hist<<<eb, 256, 0, stream>>>(edge_index, edge_type, hist);
  k_bsum<<<NBLK_SEG, 256, 0, stream>>>(hist, bsum);
  k_bscan<<<1, 1024, 0, stream>>>(bsum);
  k_offsets<<<NBLK_SEG, 256, 0, stream>>>(hist, bsum, offs, cursor);
  k_scatter<<<eb, 256, 0, stream>>>(edge_index, edge_type, cursor, ssrc);
  k_h0<<<(N_NODES * 32) / 256, 256, 0, stream>>>(node_ids, entity_emb, h_a);
  k_wcat<<<(2 * DIM * KTOT + 255) / 256, 256, 0, stream>>>(W_rel, W_self, wcat);

  const int lblocks = (N_NODES + 127) / 128;
  k_layer<<<lblocks, 256, 0, stream>>>(h_a, offs, ssrc, wcat, h_b);
  k_layer<<<lblocks, 256, 0, stream>>>(h_b, offs, ssrc, wcat + (size_t)DIM * KTOT, h_a);

  k_score<<<NQ / 4, 256, 0, stream>>>(h_a, heads, rels, tails, rel_emb, path_feat,
                                      task_idx, delta_w, lambda_lg, rule_init,
                                      (float*)d_out);
}

// Round 5
// 819.031 us; speedup vs baseline: 1.0597x; 1.0597x over previous
//
#include <hip/hip_runtime.h>

#define N_NODES 50000
#define N_ENT   100000
#define N_REL   16
#define DIM     128
#define E_EDGES 600000
#define NQ      8192
#define PATH_DIM 5
#define NK      (N_NODES * N_REL)        /* 800000 (dst,rel) segments */
#define KTOT    (N_REL * DIM + DIM)      /* 2176 = 16 rel slots + self slot */
#define NBLK_SEG (NK / 256)              /* 3125 */

typedef __attribute__((ext_vector_type(8))) short short8;
typedef __attribute__((ext_vector_type(4))) float floatx4;

static __device__ __forceinline__ short f2bf(float x) {
  unsigned u = __builtin_bit_cast(unsigned, x);
  u = (u + 0x7FFFu + ((u >> 16) & 1u)) >> 16;   // RNE
  return (short)u;
}
static __device__ __forceinline__ float bf_lo(unsigned u) {
  return __builtin_bit_cast(float, u << 16);
}
static __device__ __forceinline__ float bf_hi(unsigned u) {
  return __builtin_bit_cast(float, u & 0xffff0000u);
}
static __device__ __forceinline__ unsigned pk2(float a, float b) {
  return (unsigned)(unsigned short)f2bf(a) | ((unsigned)(unsigned short)f2bf(b) << 16);
}

static __device__ __forceinline__ int wave_incl_scan(int x) {
  int lane = threadIdx.x & 63;
  #pragma unroll
  for (int off = 1; off < 64; off <<= 1) {
    int y = __shfl_up(x, off, 64);
    if (lane >= off) x += y;
  }
  return x;
}

// ---------- edge sort by (dst*16 + etype): hist -> scan -> scatter ----------
__global__ void k_hist(const int* __restrict__ ei, const int* __restrict__ et,
                       int* __restrict__ hist) {
  int e = blockIdx.x * 256 + threadIdx.x;
  if (e >= E_EDGES) return;
  int key = ei[E_EDGES + e] * N_REL + et[e];
  atomicAdd(&hist[key], 1);
}

__global__ void k_bsum(const int* __restrict__ hist, int* __restrict__ bsum) {
  int t = threadIdx.x;
  int v = hist[blockIdx.x * 256 + t];
  #pragma unroll
  for (int off = 32; off; off >>= 1) v += __shfl_xor(v, off, 64);
  __shared__ int s4[4];
  if ((t & 63) == 0) s4[t >> 6] = v;
  __syncthreads();
  if (t == 0) bsum[blockIdx.x] = s4[0] + s4[1] + s4[2] + s4[3];
}

__global__ void k_bscan(int* __restrict__ bsum) {   // 1 block, 1024 threads, 3125 items
  int t = threadIdx.x;
  int v[4], loc[4], s = 0;
  #pragma unroll
  for (int i = 0; i < 4; i++) {
    int idx = t * 4 + i;
    v[i] = (idx < NBLK_SEG) ? bsum[idx] : 0;
    loc[i] = s; s += v[i];
  }
  int incl = wave_incl_scan(s);
  __shared__ int wsum[16];
  int wid = t >> 6, lane = t & 63;
  if (lane == 63) wsum[wid] = incl;
  __syncthreads();
  if (t < 16) {
    int x = wsum[t];
    #pragma unroll
    for (int off = 1; off < 16; off <<= 1) {
      int y = __shfl_up(x, off, 64);
      if (t >= off) x += y;
    }
    wsum[t] = x;
  }
  __syncthreads();
  int wexcl = wid ? wsum[wid - 1] : 0;
  int texcl = wexcl + incl - s;
  #pragma unroll
  for (int i = 0; i < 4; i++) {
    int idx = t * 4 + i;
    if (idx < NBLK_SEG) bsum[idx] = texcl + loc[i];
  }
}

__global__ void k_offsets(const int* __restrict__ hist, const int* __restrict__ bsum,
                          int* __restrict__ offs, int* __restrict__ cursor) {
  int t = threadIdx.x;
  int g = blockIdx.x * 256 + t;
  int v = hist[g];
  int incl = wave_incl_scan(v);
  __shared__ int wsum[4];
  int wid = t >> 6, lane = t & 63;
  if (lane == 63) wsum[wid] = incl;
  __syncthreads();
  int wexcl = 0;
  for (int i = 0; i < wid; i++) wexcl += wsum[i];
  int off = bsum[blockIdx.x] + wexcl + incl - v;
  offs[g] = off;
  cursor[g] = off;
  if (g == NK - 1) offs[NK] = off + v;
}

__global__ void k_scatter(const int* __restrict__ ei, const int* __restrict__ et,
                          int* __restrict__ cursor, int* __restrict__ ssrc) {
  int e = blockIdx.x * 256 + threadIdx.x;
  if (e >= E_EDGES) return;
  int src = ei[e];
  int key = ei[E_EDGES + e] * N_REL + et[e];
  int pos = atomicAdd(&cursor[key], 1);
  ssrc[pos] = src;
}

// ---------- h0 gather (fp32 emb -> bf16 h) ----------
__global__ void k_h0(const int* __restrict__ nid, const float* __restrict__ emb,
                     unsigned* __restrict__ h) {
  int g = blockIdx.x * 256 + threadIdx.x;     // over N*32
  int n = g >> 5;
  int q = g & 31;
  float4 v = *(const float4*)(emb + (size_t)nid[n] * DIM + q * 4);
  uint2 pk;
  pk.x = pk2(v.x, v.y);
  pk.y = pk2(v.z, v.w);
  *(uint2*)(h + (size_t)n * 64 + q * 2) = pk;
}

// ---------- W_cat bf16, layout [layer][n=out 128][k=2176 (16 rel slots | self)] ----------
__global__ void k_wcat(const float* __restrict__ wrel, const float* __restrict__ wself,
                       short* __restrict__ wcat) {
  int g = blockIdx.x * 256 + threadIdx.x;
  if (g >= 2 * DIM * KTOT) return;
  int l = g / (DIM * KTOT);
  int rem = g - l * DIM * KTOT;
  int n = rem / KTOT;
  int k = rem - n * KTOT;
  float v;
  if (k < N_REL * DIM) {
    int r = k >> 7, d = k & 127;
    v = wrel[(((size_t)l * N_REL + r) * DIM + d) * DIM + n];
  } else {
    int d = k - N_REL * DIM;
    v = wself[((size_t)l * DIM + d) * DIM + n];
  }
  wcat[g] = f2bf(v);
}

// ---------- fused layer: per-wave mean -> LDS A tile -> MFMA, no barriers ----------
// Block: 256 thr = 4 waves; each wave owns 32 rows. For r = 0..16 (16 rels + self):
//  produce A slice [32][128] bf16 in its private LDS chunk (4 rows' segments
//  processed concurrently for MLP), then 4 MFMA k-steps against B (L2-resident).
__global__ __launch_bounds__(256) void k_layer(const unsigned* __restrict__ h,
                                               const int* __restrict__ offs,
                                               const int* __restrict__ ssrc,
                                               const short* __restrict__ wb,
                                               unsigned* __restrict__ hout) {
  __shared__ short As[4][4][32][40];   // per wave, 4 k-chunks of [32 rows][40 shorts]
  __shared__ int   Soffs[4][513];
  int t = threadIdx.x;
  int w = t >> 6, lane = t & 63;
  int quad = lane >> 4, rA = lane & 15;
  int row0 = blockIdx.x * 128 + w * 32;

  // preload this wave's 513 segment offsets (rows row0..row0+31, r 0..15)
  {
    int base = row0 * N_REL;
    for (int i = lane; i < 513; i += 64) {
      int idx = base + i;
      Soffs[w][i] = (idx <= NK) ? offs[idx] : 0;
    }
  }

  floatx4 acc[2][8];
  #pragma unroll
  for (int a = 0; a < 2; a++)
    #pragma unroll
    for (int b = 0; b < 8; b++) acc[a][b] = (floatx4)0.f;

  int wchunk = lane >> 4;           // which 32-col k-chunk this lane's 2 cols fall in
  int wcol   = (lane * 2) & 31;     // col within chunk

  #pragma unroll 1
  for (int r = 0; r < 17; r++) {
    if (r < 16) {
      // ---- 4 rows' segments in flight: 4 indep idx loads + 4 indep h loads ----
      #pragma unroll 1
      for (int i0 = 0; i0 < 32; i0 += 4) {
        int p0 = Soffs[w][(i0 + 0) * 16 + r], e0 = Soffs[w][(i0 + 0) * 16 + r + 1];
        int p1 = Soffs[w][(i0 + 1) * 16 + r], e1 = Soffs[w][(i0 + 1) * 16 + r + 1];
        int p2 = Soffs[w][(i0 + 2) * 16 + r], e2 = Soffs[w][(i0 + 2) * 16 + r + 1];
        int p3 = Soffs[w][(i0 + 3) * 16 + r], e3 = Soffs[w][(i0 + 3) * 16 + r + 1];
        float i0n = 1.0f / (float)(e0 - p0 > 0 ? e0 - p0 : 1);
        float i1n = 1.0f / (float)(e1 - p1 > 0 ? e1 - p1 : 1);
        float i2n = 1.0f / (float)(e2 - p2 > 0 ? e2 - p2 : 1);
        float i3n = 1.0f / (float)(e3 - p3 > 0 ? e3 - p3 : 1);
        float a00 = 0.f, a01 = 0.f, a10 = 0.f, a11 = 0.f;
        float a20 = 0.f, a21 = 0.f, a30 = 0.f, a31 = 0.f;
        while ((p0 < e0) | (p1 < e1) | (p2 < e2) | (p3 < e3)) {
          int x0 = 0, x1 = 0, x2 = 0, x3 = 0;
          if (p0 < e0) x0 = ssrc[p0];
          if (p1 < e1) x1 = ssrc[p1];
          if (p2 < e2) x2 = ssrc[p2];
          if (p3 < e3) x3 = ssrc[p3];
          unsigned u0 = 0, u1 = 0, u2 = 0, u3 = 0;
          if (p0 < e0) u0 = h[(size_t)x0 * 64 + lane];
          if (p1 < e1) u1 = h[(size_t)x1 * 64 + lane];
          if (p2 < e2) u2 = h[(size_t)x2 * 64 + lane];
          if (p3 < e3) u3 = h[(size_t)x3 * 64 + lane];
          if (p0 < e0) { a00 += bf_lo(u0); a01 += bf_hi(u0); p0++; }
          if (p1 < e1) { a10 += bf_lo(u1); a11 += bf_hi(u1); p1++; }
          if (p2 < e2) { a20 += bf_lo(u2); a21 += bf_hi(u2); p2++; }
          if (p3 < e3) { a30 += bf_lo(u3); a31 += bf_hi(u3); p3++; }
        }
        *(unsigned*)&As[w][wchunk][i0 + 0][wcol] = pk2(a00 * i0n, a01 * i0n);
        *(unsigned*)&As[w][wchunk][i0 + 1][wcol] = pk2(a10 * i1n, a11 * i1n);
        *(unsigned*)&As[w][wchunk][i0 + 2][wcol] = pk2(a20 * i2n, a21 * i2n);
        *(unsigned*)&As[w][wchunk][i0 + 3][wcol] = pk2(a30 * i3n, a31 * i3n);
      }
    } else {
      // self slot: copy own h rows (independent loads, unrolled)
      #pragma unroll 4
      for (int i = 0; i < 32; i++) {
        int row = row0 + i;
        unsigned u = (row < N_NODES) ? h[(size_t)row * 64 + lane] : 0u;
        *(unsigned*)&As[w][wchunk][i][wcol] = u;
      }
    }
    // ---- MFMA: 4 k-steps over this 128-col slot ----
    const short* wbr = wb + r * 128;
    #pragma unroll
    for (int ks = 0; ks < 4; ks++) {
      short8 a0 = *(const short8*)&As[w][ks][rA][quad * 8];
      short8 a1 = *(const short8*)&As[w][ks][16 + rA][quad * 8];
      #pragma unroll
      for (int nt = 0; nt < 8; nt++) {
        short8 b = *(const short8*)(wbr + (size_t)(nt * 16 + rA) * KTOT + ks * 32 + quad * 8);
        acc[0][nt] = __builtin_amdgcn_mfma_f32_16x16x32_bf16(a0, b, acc[0][nt], 0, 0, 0);
        acc[1][nt] = __builtin_amdgcn_mfma_f32_16x16x32_bf16(a1, b, acc[1][nt], 0, 0, 0);
      }
    }
  }
  // ---- epilogue: relu + bf16 store. C: row=(lane>>4)*4+reg, col=lane&15 ----
  #pragma unroll
  for (int mt = 0; mt < 2; mt++)
    #pragma unroll
    for (int nt = 0; nt < 8; nt++)
      #pragma unroll
      for (int j = 0; j < 4; j++) {
        int row = row0 + mt * 16 + quad * 4 + j;
        int col = nt * 16 + rA;
        if (row < N_NODES) {
          float v = fmaxf(acc[mt][nt][j], 0.f);
          ((short*)hout)[(size_t)row * DIM + col] = f2bf(v);
        }
      }
}

// ---------- scoring (bf16 h) ----------
__global__ void k_score(const unsigned* __restrict__ h, const int* __restrict__ heads,
                        const int* __restrict__ rels, const int* __restrict__ tails,
                        const float* __restrict__ rel_emb, const float* __restrict__ path_feat,
                        const int* __restrict__ task_idx, const float* __restrict__ delta_w,
                        const float* __restrict__ lambda_logit, const float* __restrict__ rule_init,
                        float* __restrict__ out) {
  int q = (blockIdx.x * 256 + threadIdx.x) >> 6;
  int lane = threadIdx.x & 63;
  int hd = heads[q], tl = tails[q], rl = rels[q];
  unsigned ua = h[(size_t)hd * 64 + lane];
  unsigned uc = h[(size_t)tl * 64 + lane];
  float2 r = *(const float2*)(rel_emb + (size_t)rl * DIM + lane * 2);
  float s = bf_lo(ua) * r.x * bf_lo(uc) + bf_hi(ua) * r.y * bf_hi(uc);
  #pragma unroll
  for (int off = 32; off; off >>= 1) s += __shfl_xor(s, off, 64);
  if (lane == 0) {
    int task = task_idx[0];
    float sp = 0.f;
    #pragma unroll
    for (int p = 0; p < PATH_DIM; p++)
      sp += path_feat[q * PATH_DIM + p] *
            (rule_init[task * PATH_DIM + p] + delta_w[task * PATH_DIM + p]);
    float lam = 1.f / (1.f + __expf(-lambda_logit[task]));
    out[q] = lam * s + (1.f - lam) * sp;
  }
}

extern "C" void kernel_launch(void* const* d_in, const int* in_sizes, int n_in,
                              void* d_out, int out_size, void* d_ws, size_t ws_size,
                              hipStream_t stream) {
  const int*   node_ids   = (const int*)d_in[0];
  const int*   edge_index = (const int*)d_in[1];
  const int*   edge_type  = (const int*)d_in[2];
  const int*   heads      = (const int*)d_in[3];
  const int*   rels       = (const int*)d_in[4];
  const int*   tails      = (const int*)d_in[5];
  const float* path_feat  = (const float*)d_in[6];
  const int*   task_idx   = (const int*)d_in[7];
  const float* entity_emb = (const float*)d_in[8];
  const float* rel_emb    = (const float*)d_in[9];
  const float* W_self     = (const float*)d_in[10];
  const float* W_rel      = (const float*)d_in[11];
  const float* delta_w    = (const float*)d_in[12];
  const float* lambda_lg  = (const float*)d_in[13];
  const float* rule_init  = (const float*)d_in[14];

  char* ws = (char*)d_ws;
  size_t off = 0;
  auto alloc = [&](size_t bytes) -> void* {
    void* p = ws + off;
    off = (off + bytes + 255) & ~(size_t)255;
    return p;
  };
  unsigned* h_a    = (unsigned*)alloc((size_t)N_NODES * DIM * 2);
  unsigned* h_b    = (unsigned*)alloc((size_t)N_NODES * DIM * 2);
  short*    wcat   = (short*)alloc((size_t)2 * DIM * KTOT * 2);
  int*      offs   = (int*)alloc((size_t)(NK + 1) * 4);
  int*      ssrc   = (int*)alloc((size_t)E_EDGES * 4);
  int*      hist   = (int*)alloc((size_t)(NK + 1) * 4);
  int*      cursor = (int*)alloc((size_t)NK * 4);
  int*      bsum   = (int*)alloc((size_t)NBLK_SEG * 4);

  hipMemsetAsync(hist, 0, (size_t)(NK + 1) * 4, stream);
  int eb = (E_EDGES + 255) / 256;
  k_hist<<<eb, 256, 0, stream>>>(edge_index, edge_type, hist);
  k_bsum<<<NBLK_SEG, 256, 0, stream>>>(hist, bsum);
  k_bscan<<<1, 1024, 0, stream>>>(bsum);
  k_offsets<<<NBLK_SEG, 256, 0, stream>>>(hist, bsum, offs, cursor);
  k_scatter<<<eb, 256, 0, stream>>>(edge_index, edge_type, cursor, ssrc);
  k_h0<<<(N_NODES * 32) / 256, 256, 0, stream>>>(node_ids, entity_emb, h_a);
  k_wcat<<<(2 * DIM * KTOT + 255) / 256, 256, 0, stream>>>(W_rel, W_self, wcat);

  const int lblocks = (N_NODES + 127) / 128;
  k_layer<<<lblocks, 256, 0, stream>>>(h_a, offs, ssrc, wcat, h_b);
  k_layer<<<lblocks, 256, 0, stream>>>(h_b, offs, ssrc, wcat + (size_t)DIM * KTOT, h_a);

  k_score<<<NQ / 4, 256, 0, stream>>>(h_a, heads, rels, tails, rel_emb, path_feat,
                                      task_idx, delta_w, lambda_lg, rule_init,
                                      (float*)d_out);
}

// Round 6
// 725.648 us; speedup vs baseline: 1.1960x; 1.1287x over previous
//
#include <hip/hip_runtime.h>

#define N_NODES 50000
#define N_ENT   100000
#define N_REL   16
#define DIM     128
#define E_EDGES 600000
#define NQ      8192
#define PATH_DIM 5
#define NK      (N_NODES * N_REL)        /* 800000 (rel,dst) segments */
#define KTOT    (N_REL * DIM + DIM)      /* 2176 = 16 rel slots + self slot */
#define NBLK_SEG (NK / 256)              /* 3125 */

typedef __attribute__((ext_vector_type(8))) short short8;
typedef __attribute__((ext_vector_type(4))) float floatx4;

static __device__ __forceinline__ short f2bf(float x) {
  unsigned u = __builtin_bit_cast(unsigned, x);
  u = (u + 0x7FFFu + ((u >> 16) & 1u)) >> 16;   // RNE
  return (short)u;
}
static __device__ __forceinline__ float bf_lo(unsigned u) {
  return __builtin_bit_cast(float, u << 16);
}
static __device__ __forceinline__ float bf_hi(unsigned u) {
  return __builtin_bit_cast(float, u & 0xffff0000u);
}
static __device__ __forceinline__ unsigned pk2(float a, float b) {
  return (unsigned)(unsigned short)f2bf(a) | ((unsigned)(unsigned short)f2bf(b) << 16);
}

static __device__ __forceinline__ int wave_incl_scan(int x) {
  int lane = threadIdx.x & 63;
  #pragma unroll
  for (int off = 1; off < 64; off <<= 1) {
    int y = __shfl_up(x, off, 64);
    if (lane >= off) x += y;
  }
  return x;
}

// ---------- edge sort by (etype*N + dst): hist -> scan -> scatter ----------
__global__ void k_hist(const int* __restrict__ ei, const int* __restrict__ et,
                       int* __restrict__ hist) {
  int e = blockIdx.x * 256 + threadIdx.x;
  if (e >= E_EDGES) return;
  int key = et[e] * N_NODES + ei[E_EDGES + e];
  atomicAdd(&hist[key], 1);
}

__global__ void k_bsum(const int* __restrict__ hist, int* __restrict__ bsum) {
  int t = threadIdx.x;
  int v = hist[blockIdx.x * 256 + t];
  #pragma unroll
  for (int off = 32; off; off >>= 1) v += __shfl_xor(v, off, 64);
  __shared__ int s4[4];
  if ((t & 63) == 0) s4[t >> 6] = v;
  __syncthreads();
  if (t == 0) bsum[blockIdx.x] = s4[0] + s4[1] + s4[2] + s4[3];
}

__global__ void k_bscan(int* __restrict__ bsum) {   // 1 block, 1024 threads, 3125 items
  int t = threadIdx.x;
  int v[4], loc[4], s = 0;
  #pragma unroll
  for (int i = 0; i < 4; i++) {
    int idx = t * 4 + i;
    v[i] = (idx < NBLK_SEG) ? bsum[idx] : 0;
    loc[i] = s; s += v[i];
  }
  int incl = wave_incl_scan(s);
  __shared__ int wsum[16];
  int wid = t >> 6, lane = t & 63;
  if (lane == 63) wsum[wid] = incl;
  __syncthreads();
  if (t < 16) {
    int x = wsum[t];
    #pragma unroll
    for (int off = 1; off < 16; off <<= 1) {
      int y = __shfl_up(x, off, 64);
      if (t >= off) x += y;
    }
    wsum[t] = x;
  }
  __syncthreads();
  int wexcl = wid ? wsum[wid - 1] : 0;
  int texcl = wexcl + incl - s;
  #pragma unroll
  for (int i = 0; i < 4; i++) {
    int idx = t * 4 + i;
    if (idx < NBLK_SEG) bsum[idx] = texcl + loc[i];
  }
}

__global__ void k_offsets(const int* __restrict__ hist, const int* __restrict__ bsum,
                          int* __restrict__ offs, int* __restrict__ cursor) {
  int t = threadIdx.x;
  int g = blockIdx.x * 256 + t;
  int v = hist[g];
  int incl = wave_incl_scan(v);
  __shared__ int wsum[4];
  int wid = t >> 6, lane = t & 63;
  if (lane == 63) wsum[wid] = incl;
  __syncthreads();
  int wexcl = 0;
  for (int i = 0; i < wid; i++) wexcl += wsum[i];
  int off = bsum[blockIdx.x] + wexcl + incl - v;
  offs[g] = off;
  cursor[g] = off;
  if (g == NK - 1) offs[NK] = off + v;
}

__global__ void k_scatter(const int* __restrict__ ei, const int* __restrict__ et,
                          int* __restrict__ cursor, int* __restrict__ ssrc) {
  int e = blockIdx.x * 256 + threadIdx.x;
  if (e >= E_EDGES) return;
  int src = ei[e];
  int key = et[e] * N_NODES + ei[E_EDGES + e];
  int pos = atomicAdd(&cursor[key], 1);
  ssrc[pos] = src;
}

// ---------- h0 gather (fp32 emb -> bf16 h) ----------
__global__ void k_h0(const int* __restrict__ nid, const float* __restrict__ emb,
                     unsigned* __restrict__ h) {
  int g = blockIdx.x * 256 + threadIdx.x;     // over N*32
  int n = g >> 5;
  int q = g & 31;
  float4 v = *(const float4*)(emb + (size_t)nid[n] * DIM + q * 4);
  uint2 pk;
  pk.x = pk2(v.x, v.y);
  pk.y = pk2(v.z, v.w);
  *(uint2*)(h + (size_t)n * 64 + q * 2) = pk;
}

// ---------- W_cat bf16, layout [layer][n=out 128][k=2176 (16 rel slots | self)] ----------
__global__ void k_wcat(const float* __restrict__ wrel, const float* __restrict__ wself,
                       short* __restrict__ wcat) {
  int g = blockIdx.x * 256 + threadIdx.x;
  if (g >= 2 * DIM * KTOT) return;
  int l = g / (DIM * KTOT);
  int rem = g - l * DIM * KTOT;
  int n = rem / KTOT;
  int k = rem - n * KTOT;
  float v;
  if (k < N_REL * DIM) {
    int r = k >> 7, d = k & 127;
    v = wrel[(((size_t)l * N_REL + r) * DIM + d) * DIM + n];
  } else {
    int d = k - N_REL * DIM;
    v = wself[((size_t)l * DIM + d) * DIM + n];
  }
  wcat[g] = f2bf(v);
}

// ---------- fused layer: per-wave edge-stream mean -> LDS A tile -> MFMA ----------
// Block: 256 thr = 4 waves; each wave owns 16 rows. Edges sorted (rel, dst) so the
// wave's edges per rel-slot are ONE contiguous run: coalesced idx load + readlane
// broadcast + 16 independent h-row loads per latency hop.
__global__ __launch_bounds__(256) void k_layer(const unsigned* __restrict__ h,
                                               const int* __restrict__ offs,
                                               const int* __restrict__ ssrc,
                                               const short* __restrict__ wb,
                                               unsigned* __restrict__ hout) {
  __shared__ short As[4][4][16][40];   // per wave, 4 k-chunks of [16 rows][40 shorts]
  __shared__ int   Soffs[4][272];      // per wave, 16 rels x 17 boundaries
  int t = threadIdx.x;
  int w = t >> 6, lane = t & 63;
  int quad = lane >> 4, rA = lane & 15;
  int row0 = blockIdx.x * 64 + w * 16;

  // preload boundaries: Soffs[w][r*17+i] = offs[r*N + min(row0+i, N)]
  for (int i = lane; i < 272; i += 64) {
    int r = i / 17;
    int ii = i - r * 17;
    int rowc = row0 + ii;
    if (rowc > N_NODES) rowc = N_NODES;
    Soffs[w][i] = offs[r * N_NODES + rowc];
  }

  floatx4 acc[8];
  #pragma unroll
  for (int b = 0; b < 8; b++) acc[b] = (floatx4)0.f;

  int wchunk = lane >> 4;           // which 32-col k-chunk this lane's 2 cols fall in
  int wcol   = (lane * 2) & 31;     // col within chunk

  #pragma unroll 1
  for (int r = 0; r < 17; r++) {
    if (r < 16) {
      int sbase = r * 17;
      int b0   = Soffs[w][sbase];
      int bend = Soffs[w][sbase + 16];
      float a0s = 0.f, a1s = 0.f;
      int seg = 0;
      int segstart = b0;
      int segend = Soffs[w][sbase + 1];
      #pragma unroll 1
      for (int chunk = b0; chunk < bend; chunk += 64) {
        int myp = chunk + lane;
        int myidx = (myp < bend) ? ssrc[myp] : 0;
        #pragma unroll 1
        for (int g = 0; g < 4; g++) {
          int jb = chunk + g * 16;
          if (jb >= bend) break;
          unsigned u[16];
          #pragma unroll
          for (int j = 0; j < 16; j++) {
            int src = __shfl(myidx, g * 16 + j);
            u[j] = (jb + j < bend) ? h[(size_t)src * 64 + lane] : 0u;
          }
          #pragma unroll
          for (int j = 0; j < 16; j++) {
            int p = jb + j;
            if (p < bend) {
              while (p >= segend) {   // flush segments up to the one owning p
                int cnt = segend - segstart;
                float inv = 1.0f / (float)(cnt > 0 ? cnt : 1);
                *(unsigned*)&As[w][wchunk][seg][wcol] = pk2(a0s * inv, a1s * inv);
                a0s = 0.f; a1s = 0.f;
                seg++;
                segstart = segend;
                segend = Soffs[w][sbase + seg + 1];
              }
              unsigned uu = u[j];
              a0s += bf_lo(uu); a1s += bf_hi(uu);
            }
          }
        }
      }
      while (seg < 16) {   // flush trailing segments (incl. empty)
        int cnt = segend - segstart;
        float inv = 1.0f / (float)(cnt > 0 ? cnt : 1);
        *(unsigned*)&As[w][wchunk][seg][wcol] = pk2(a0s * inv, a1s * inv);
        a0s = 0.f; a1s = 0.f;
        seg++;
        if (seg < 16) { segstart = segend; segend = Soffs[w][sbase + seg + 1]; }
      }
    } else {
      // self slot: copy own h rows
      #pragma unroll 4
      for (int i = 0; i < 16; i++) {
        int row = row0 + i;
        unsigned uu = (row < N_NODES) ? h[(size_t)row * 64 + lane] : 0u;
        *(unsigned*)&As[w][wchunk][i][wcol] = uu;
      }
    }
    // ---- MFMA: 4 k-steps over this 128-col slot ----
    const short* wbr = wb + r * 128;
    #pragma unroll
    for (int ks = 0; ks < 4; ks++) {
      short8 a0 = *(const short8*)&As[w][ks][rA][quad * 8];
      #pragma unroll
      for (int nt = 0; nt < 8; nt++) {
        short8 b = *(const short8*)(wbr + (size_t)(nt * 16 + rA) * KTOT + ks * 32 + quad * 8);
        acc[nt] = __builtin_amdgcn_mfma_f32_16x16x32_bf16(a0, b, acc[nt], 0, 0, 0);
      }
    }
  }
  // ---- epilogue: relu + bf16 store. C: row=(lane>>4)*4+reg, col=lane&15 ----
  #pragma unroll
  for (int nt = 0; nt < 8; nt++)
    #pragma unroll
    for (int j = 0; j < 4; j++) {
      int row = row0 + quad * 4 + j;
      int col = nt * 16 + rA;
      if (row < N_NODES) {
        float v = fmaxf(acc[nt][j], 0.f);
        ((short*)hout)[(size_t)row * DIM + col] = f2bf(v);
      }
    }
}

// ---------- scoring (bf16 h) ----------
__global__ void k_score(const unsigned* __restrict__ h, const int* __restrict__ heads,
                        const int* __restrict__ rels, const int* __restrict__ tails,
                        const float* __restrict__ rel_emb, const float* __restrict__ path_feat,
                        const int* __restrict__ task_idx, const float* __restrict__ delta_w,
                        const float* __restrict__ lambda_logit, const float* __restrict__ rule_init,
                        float* __restrict__ out) {
  int q = (blockIdx.x * 256 + threadIdx.x) >> 6;
  int lane = threadIdx.x & 63;
  int hd = heads[q], tl = tails[q], rl = rels[q];
  unsigned ua = h[(size_t)hd * 64 + lane];
  unsigned uc = h[(size_t)tl * 64 + lane];
  float2 r = *(const float2*)(rel_emb + (size_t)rl * DIM + lane * 2);
  float s = bf_lo(ua) * r.x * bf_lo(uc) + bf_hi(ua) * r.y * bf_hi(uc);
  #pragma unroll
  for (int off = 32; off; off >>= 1) s += __shfl_xor(s, off, 64);
  if (lane == 0) {
    int task = task_idx[0];
    float sp = 0.f;
    #pragma unroll
    for (int p = 0; p < PATH_DIM; p++)
      sp += path_feat[q * PATH_DIM + p] *
            (rule_init[task * PATH_DIM + p] + delta_w[task * PATH_DIM + p]);
    float lam = 1.f / (1.f + __expf(-lambda_logit[task]));
    out[q] = lam * s + (1.f - lam) * sp;
  }
}

extern "C" void kernel_launch(void* const* d_in, const int* in_sizes, int n_in,
                              void* d_out, int out_size, void* d_ws, size_t ws_size,
                              hipStream_t stream) {
  const int*   node_ids   = (const int*)d_in[0];
  const int*   edge_index = (const int*)d_in[1];
  const int*   edge_type  = (const int*)d_in[2];
  const int*   heads      = (const int*)d_in[3];
  const int*   rels       = (const int*)d_in[4];
  const int*   tails      = (const int*)d_in[5];
  const float* path_feat  = (const float*)d_in[6];
  const int*   task_idx   = (const int*)d_in[7];
  const float* entity_emb = (const float*)d_in[8];
  const float* rel_emb    = (const float*)d_in[9];
  const float* W_self     = (const float*)d_in[10];
  const float* W_rel      = (const float*)d_in[11];
  const float* delta_w    = (const float*)d_in[12];
  const float* lambda_lg  = (const float*)d_in[13];
  const float* rule_init  = (const float*)d_in[14];

  char* ws = (char*)d_ws;
  size_t off = 0;
  auto alloc = [&](size_t bytes) -> void* {
    void* p = ws + off;
    off = (off + bytes + 255) & ~(size_t)255;
    return p;
  };
  unsigned* h_a    = (unsigned*)alloc((size_t)N_NODES * DIM * 2);
  unsigned* h_b    = (unsigned*)alloc((size_t)N_NODES * DIM * 2);
  short*    wcat   = (short*)alloc((size_t)2 * DIM * KTOT * 2);
  int*      offs   = (int*)alloc((size_t)(NK + 1) * 4);
  int*      ssrc   = (int*)alloc((size_t)E_EDGES * 4);
  int*      hist   = (int*)alloc((size_t)(NK + 1) * 4);
  int*      cursor = (int*)alloc((size_t)NK * 4);
  int*      bsum   = (int*)alloc((size_t)NBLK_SEG * 4);

  hipMemsetAsync(hist, 0, (size_t)(NK + 1) * 4, stream);
  int eb = (E_EDGES + 255) / 256;
  k_hist<<<eb, 256, 0, stream>>>(edge_index, edge_type, hist);
  k_bsum<<<NBLK_SEG, 256, 0, stream>>>(hist, bsum);
  k_bscan<<<1, 1024, 0, stream>>>(bsum);
  k_offsets<<<NBLK_SEG, 256, 0, stream>>>(hist, bsum, offs, cursor);
  k_scatter<<<eb, 256, 0, stream>>>(edge_index, edge_type, cursor, ssrc);
  k_h0<<<(N_NODES * 32) / 256, 256, 0, stream>>>(node_ids, entity_emb, h_a);
  k_wcat<<<(2 * DIM * KTOT + 255) / 256, 256, 0, stream>>>(W_rel, W_self, wcat);

  const int lblocks = (N_NODES + 63) / 64;
  k_layer<<<lblocks, 256, 0, stream>>>(h_a, offs, ssrc, wcat, h_b);
  k_layer<<<lblocks, 256, 0, stream>>>(h_b, offs, ssrc, wcat + (size_t)DIM * KTOT, h_a);

  k_score<<<NQ / 4, 256, 0, stream>>>(h_a, heads, rels, tails, rel_emb, path_feat,
                                      task_idx, delta_w, lambda_lg, rule_init,
                                      (float*)d_out);
}

// Round 7
// 718.536 us; speedup vs baseline: 1.2079x; 1.0099x over previous
//
#include <hip/hip_runtime.h>

#define N_NODES 50000
#define N_ENT   100000
#define N_REL   16
#define DIM     128
#define E_EDGES 600000
#define NQ      8192
#define PATH_DIM 5
#define NK      (N_NODES * N_REL)        /* 800000 (rel,dst) segments */
#define KTOT    (N_REL * DIM + DIM)      /* 2176 = 16 rel slots + self slot */
#define NBLK_SEG (NK / 256)              /* 3125 */

typedef __attribute__((ext_vector_type(8))) short short8;
typedef __attribute__((ext_vector_type(4))) float floatx4;

static __device__ __forceinline__ short f2bf(float x) {
  unsigned u = __builtin_bit_cast(unsigned, x);
  u = (u + 0x7FFFu + ((u >> 16) & 1u)) >> 16;   // RNE
  return (short)u;
}
static __device__ __forceinline__ float bf_lo(unsigned u) {
  return __builtin_bit_cast(float, u << 16);
}
static __device__ __forceinline__ float bf_hi(unsigned u) {
  return __builtin_bit_cast(float, u & 0xffff0000u);
}
static __device__ __forceinline__ unsigned pk2(float a, float b) {
  return (unsigned)(unsigned short)f2bf(a) | ((unsigned)(unsigned short)f2bf(b) << 16);
}

static __device__ __forceinline__ int wave_incl_scan(int x) {
  int lane = threadIdx.x & 63;
  #pragma unroll
  for (int off = 1; off < 64; off <<= 1) {
    int y = __shfl_up(x, off, 64);
    if (lane >= off) x += y;
  }
  return x;
}

// ---------- edge sort by (etype*N + dst): hist -> scan -> scatter ----------
__global__ void k_hist(const int* __restrict__ ei, const int* __restrict__ et,
                       int* __restrict__ hist) {
  int e = blockIdx.x * 256 + threadIdx.x;
  if (e >= E_EDGES) return;
  int key = et[e] * N_NODES + ei[E_EDGES + e];
  atomicAdd(&hist[key], 1);
}

__global__ void k_bsum(const int* __restrict__ hist, int* __restrict__ bsum) {
  int t = threadIdx.x;
  int v = hist[blockIdx.x * 256 + t];
  #pragma unroll
  for (int off = 32; off; off >>= 1) v += __shfl_xor(v, off, 64);
  __shared__ int s4[4];
  if ((t & 63) == 0) s4[t >> 6] = v;
  __syncthreads();
  if (t == 0) bsum[blockIdx.x] = s4[0] + s4[1] + s4[2] + s4[3];
}

__global__ void k_bscan(int* __restrict__ bsum) {   // 1 block, 1024 threads, 3125 items
  int t = threadIdx.x;
  int v[4], loc[4], s = 0;
  #pragma unroll
  for (int i = 0; i < 4; i++) {
    int idx = t * 4 + i;
    v[i] = (idx < NBLK_SEG) ? bsum[idx] : 0;
    loc[i] = s; s += v[i];
  }
  int incl = wave_incl_scan(s);
  __shared__ int wsum[16];
  int wid = t >> 6, lane = t & 63;
  if (lane == 63) wsum[wid] = incl;
  __syncthreads();
  if (t < 16) {
    int x = wsum[t];
    #pragma unroll
    for (int off = 1; off < 16; off <<= 1) {
      int y = __shfl_up(x, off, 64);
      if (t >= off) x += y;
    }
    wsum[t] = x;
  }
  __syncthreads();
  int wexcl = wid ? wsum[wid - 1] : 0;
  int texcl = wexcl + incl - s;
  #pragma unroll
  for (int i = 0; i < 4; i++) {
    int idx = t * 4 + i;
    if (idx < NBLK_SEG) bsum[idx] = texcl + loc[i];
  }
}

__global__ void k_offsets(const int* __restrict__ hist, const int* __restrict__ bsum,
                          int* __restrict__ offs, int* __restrict__ cursor) {
  int t = threadIdx.x;
  int g = blockIdx.x * 256 + t;
  int v = hist[g];
  int incl = wave_incl_scan(v);
  __shared__ int wsum[4];
  int wid = t >> 6, lane = t & 63;
  if (lane == 63) wsum[wid] = incl;
  __syncthreads();
  int wexcl = 0;
  for (int i = 0; i < wid; i++) wexcl += wsum[i];
  int off = bsum[blockIdx.x] + wexcl + incl - v;
  offs[g] = off;
  cursor[g] = off;
  if (g == NK - 1) offs[NK] = off + v;
}

// writes ssrc (source idx) and spck (dst 16b | bf16(1/cnt) 16b)
__global__ void k_scatter(const int* __restrict__ ei, const int* __restrict__ et,
                          const int* __restrict__ hist, int* __restrict__ cursor,
                          int* __restrict__ ssrc, unsigned* __restrict__ spck) {
  int e = blockIdx.x * 256 + threadIdx.x;
  if (e >= E_EDGES) return;
  int src = ei[e];
  int dst = ei[E_EDGES + e];
  int key = et[e] * N_NODES + dst;
  int pos = atomicAdd(&cursor[key], 1);
  int cnt = hist[key];
  float w = 1.0f / (float)cnt;
  ssrc[pos] = src;
  spck[pos] = (unsigned)dst | ((unsigned)(unsigned short)f2bf(w) << 16);
}

// ---------- h0 gather (fp32 emb -> bf16 h) ----------
__global__ void k_h0(const int* __restrict__ nid, const float* __restrict__ emb,
                     unsigned* __restrict__ h) {
  int g = blockIdx.x * 256 + threadIdx.x;     // over N*32
  int n = g >> 5;
  int q = g & 31;
  float4 v = *(const float4*)(emb + (size_t)nid[n] * DIM + q * 4);
  uint2 pk;
  pk.x = pk2(v.x, v.y);
  pk.y = pk2(v.z, v.w);
  *(uint2*)(h + (size_t)n * 64 + q * 2) = pk;
}

// ---------- W_cat bf16, layout [layer][n=out 128][k=2176 (16 rel slots | self)] ----------
__global__ void k_wcat(const float* __restrict__ wrel, const float* __restrict__ wself,
                       short* __restrict__ wcat) {
  int g = blockIdx.x * 256 + threadIdx.x;
  if (g >= 2 * DIM * KTOT) return;
  int l = g / (DIM * KTOT);
  int rem = g - l * DIM * KTOT;
  int n = rem / KTOT;
  int k = rem - n * KTOT;
  float v;
  if (k < N_REL * DIM) {
    int r = k >> 7, d = k & 127;
    v = wrel[(((size_t)l * N_REL + r) * DIM + d) * DIM + n];
  } else {
    int d = k - N_REL * DIM;
    v = wself[((size_t)l * DIM + d) * DIM + n];
  }
  wcat[g] = f2bf(v);
}

// ---------- fused layer: branchless edge-stream mean -> LDS A tile -> MFMA ----------
// Block: 256 thr = 4 waves; each wave owns 16 rows. Edges sorted (rel, dst):
// per slot the wave's edges are one contiguous run. Per 16-edge group:
// 2 coalesced loads + 32 shuffles + 16 UNCONDITIONAL h-row loads (batched under
// one vmcnt), then pure-VALU pre-weighted accumulation with write-only flushes.
__global__ __launch_bounds__(256) void k_layer(const unsigned* __restrict__ h,
                                               const int* __restrict__ offs,
                                               const int* __restrict__ ssrc,
                                               const unsigned* __restrict__ spck,
                                               const short* __restrict__ wb,
                                               unsigned* __restrict__ hout) {
  __shared__ short As[4][4][16][40];   // per wave, 4 k-chunks of [16 rows][40 shorts]
  int t = threadIdx.x;
  int w = t >> 6, lane = t & 63;
  int quad = lane >> 4, rA = lane & 15;
  int row0 = blockIdx.x * 64 + w * 16;

  // slot boundaries in registers: lane (2r+which) holds offs[r*N + row0 + 16*which]
  int bnd = 0;
  if (lane < 32) {
    int r = lane >> 1, which = lane & 1;
    int rowc = row0 + which * 16;
    if (rowc > N_NODES) rowc = N_NODES;
    bnd = offs[r * N_NODES + rowc];
  }

  floatx4 acc[8];
  #pragma unroll
  for (int b = 0; b < 8; b++) acc[b] = (floatx4)0.f;

  int wchunk = lane >> 4;           // which 32-col k-chunk this lane's 2 cols fall in
  int wcol   = (lane * 2) & 31;     // col within chunk

  #pragma unroll 1
  for (int r = 0; r < 17; r++) {
    if (r < 16) {
      int b0   = __shfl(bnd, r * 2);
      int bend = __shfl(bnd, r * 2 + 1);
      // pre-clear the 16 A rows (covers empty segments); fire-and-forget writes
      #pragma unroll
      for (int i = 0; i < 16; i++)
        *(unsigned*)&As[w][wchunk][i][wcol] = 0u;
      float a0 = 0.f, a1 = 0.f;
      int cur = -1;
      #pragma unroll 1
      for (int chunk = b0; chunk < bend; chunk += 64) {
        int clampp = min(chunk + lane, bend - 1);
        int mysrc = ssrc[clampp];
        unsigned mypk = spck[clampp];
        #pragma unroll 1
        for (int g = 0; g < 4; g++) {
          int jb = chunk + g * 16;
          if (jb >= bend) break;
          int      sj[16];
          unsigned pj[16];
          #pragma unroll
          for (int j = 0; j < 16; j++) {
            sj[j] = __shfl(mysrc, g * 16 + j);
            pj[j] = __shfl(mypk, g * 16 + j);
          }
          unsigned u[16];
          #pragma unroll
          for (int j = 0; j < 16; j++)
            u[j] = h[(size_t)sj[j] * 64 + lane];   // unconditional (clamped addr)
          #pragma unroll
          for (int j = 0; j < 16; j++) {
            int p = jb + j;
            if (p < bend) {                        // wave-uniform
              int dstj = (int)(pj[j] & 0xffffu);
              if (dstj != cur) {                   // wave-uniform
                if (cur >= 0)
                  *(unsigned*)&As[w][wchunk][cur - row0][wcol] = pk2(a0, a1);
                cur = dstj; a0 = 0.f; a1 = 0.f;
              }
              float wgt = bf_hi(pj[j]);
              a0 += bf_lo(u[j]) * wgt;
              a1 += bf_hi(u[j]) * wgt;
            }
          }
        }
      }
      if (cur >= 0)
        *(unsigned*)&As[w][wchunk][cur - row0][wcol] = pk2(a0, a1);
    } else {
      // self slot: copy own h rows
      #pragma unroll 4
      for (int i = 0; i < 16; i++) {
        int row = row0 + i;
        unsigned uu = (row < N_NODES) ? h[(size_t)row * 64 + lane] : 0u;
        *(unsigned*)&As[w][wchunk][i][wcol] = uu;
      }
    }
    // ---- MFMA: 4 k-steps over this 128-col slot ----
    const short* wbr = wb + r * 128;
    #pragma unroll
    for (int ks = 0; ks < 4; ks++) {
      short8 a0v = *(const short8*)&As[w][ks][rA][quad * 8];
      #pragma unroll
      for (int nt = 0; nt < 8; nt++) {
        short8 b = *(const short8*)(wbr + (size_t)(nt * 16 + rA) * KTOT + ks * 32 + quad * 8);
        acc[nt] = __builtin_amdgcn_mfma_f32_16x16x32_bf16(a0v, b, acc[nt], 0, 0, 0);
      }
    }
  }
  // ---- epilogue: relu + bf16 store. C: row=(lane>>4)*4+reg, col=lane&15 ----
  #pragma unroll
  for (int nt = 0; nt < 8; nt++)
    #pragma unroll
    for (int j = 0; j < 4; j++) {
      int row = row0 + quad * 4 + j;
      int col = nt * 16 + rA;
      if (row < N_NODES) {
        float v = fmaxf(acc[nt][j], 0.f);
        ((short*)hout)[(size_t)row * DIM + col] = f2bf(v);
      }
    }
}

// ---------- scoring (bf16 h) ----------
__global__ void k_score(const unsigned* __restrict__ h, const int* __restrict__ heads,
                        const int* __restrict__ rels, const int* __restrict__ tails,
                        const float* __restrict__ rel_emb, const float* __restrict__ path_feat,
                        const int* __restrict__ task_idx, const float* __restrict__ delta_w,
                        const float* __restrict__ lambda_logit, const float* __restrict__ rule_init,
                        float* __restrict__ out) {
  int q = (blockIdx.x * 256 + threadIdx.x) >> 6;
  int lane = threadIdx.x & 63;
  int hd = heads[q], tl = tails[q], rl = rels[q];
  unsigned ua = h[(size_t)hd * 64 + lane];
  unsigned uc = h[(size_t)tl * 64 + lane];
  float2 r = *(const float2*)(rel_emb + (size_t)rl * DIM + lane * 2);
  float s = bf_lo(ua) * r.x * bf_lo(uc) + bf_hi(ua) * r.y * bf_hi(uc);
  #pragma unroll
  for (int off = 32; off; off >>= 1) s += __shfl_xor(s, off, 64);
  if (lane == 0) {
    int task = task_idx[0];
    float sp = 0.f;
    #pragma unroll
    for (int p = 0; p < PATH_DIM; p++)
      sp += path_feat[q * PATH_DIM + p] *
            (rule_init[task * PATH_DIM + p] + delta_w[task * PATH_DIM + p]);
    float lam = 1.f / (1.f + __expf(-lambda_logit[task]));
    out[q] = lam * s + (1.f - lam) * sp;
  }
}

extern "C" void kernel_launch(void* const* d_in, const int* in_sizes, int n_in,
                              void* d_out, int out_size, void* d_ws, size_t ws_size,
                              hipStream_t stream) {
  const int*   node_ids   = (const int*)d_in[0];
  const int*   edge_index = (const int*)d_in[1];
  const int*   edge_type  = (const int*)d_in[2];
  const int*   heads      = (const int*)d_in[3];
  const int*   rels       = (const int*)d_in[4];
  const int*   tails      = (const int*)d_in[5];
  const float* path_feat  = (const float*)d_in[6];
  const int*   task_idx   = (const int*)d_in[7];
  const float* entity_emb = (const float*)d_in[8];
  const float* rel_emb    = (const float*)d_in[9];
  const float* W_self     = (const float*)d_in[10];
  const float* W_rel      = (const float*)d_in[11];
  const float* delta_w    = (const float*)d_in[12];
  const float* lambda_lg  = (const float*)d_in[13];
  const float* rule_init  = (const float*)d_in[14];

  char* ws = (char*)d_ws;
  size_t off = 0;
  auto alloc = [&](size_t bytes) -> void* {
    void* p = ws + off;
    off = (off + bytes + 255) & ~(size_t)255;
    return p;
  };
  unsigned* h_a    = (unsigned*)alloc((size_t)N_NODES * DIM * 2);
  unsigned* h_b    = (unsigned*)alloc((size_t)N_NODES * DIM * 2);
  short*    wcat   = (short*)alloc((size_t)2 * DIM * KTOT * 2);
  int*      offs   = (int*)alloc((size_t)(NK + 1) * 4);
  int*      ssrc   = (int*)alloc((size_t)E_EDGES * 4);
  unsigned* spck   = (unsigned*)alloc((size_t)E_EDGES * 4);
  int*      hist   = (int*)alloc((size_t)(NK + 1) * 4);
  int*      cursor = (int*)alloc((size_t)NK * 4);
  int*      bsum   = (int*)alloc((size_t)NBLK_SEG * 4);

  hipMemsetAsync(hist, 0, (size_t)(NK + 1) * 4, stream);
  int eb = (E_EDGES + 255) / 256;
  k_hist<<<eb, 256, 0, stream>>>(edge_index, edge_type, hist);
  k_bsum<<<NBLK_SEG, 256, 0, stream>>>(hist, bsum);
  k_bscan<<<1, 1024, 0, stream>>>(bsum);
  k_offsets<<<NBLK_SEG, 256, 0, stream>>>(hist, bsum, offs, cursor);
  k_scatter<<<eb, 256, 0, stream>>>(edge_index, edge_type, hist, cursor, ssrc, spck);
  k_h0<<<(N_NODES * 32) / 256, 256, 0, stream>>>(node_ids, entity_emb, h_a);
  k_wcat<<<(2 * DIM * KTOT + 255) / 256, 256, 0, stream>>>(W_rel, W_self, wcat);

  const int lblocks = (N_NODES + 63) / 64;
  k_layer<<<lblocks, 256, 0, stream>>>(h_a, offs, ssrc, spck, wcat, h_b);
  k_layer<<<lblocks, 256, 0, stream>>>(h_b, offs, ssrc, spck,
                                       wcat + (size_t)DIM * KTOT, h_a);

  k_score<<<NQ / 4, 256, 0, stream>>>(h_a, heads, rels, tails, rel_emb, path_feat,
                                      task_idx, delta_w, lambda_lg, rule_init,
                                      (float*)d_out);
}

// Round 8
// 717.466 us; speedup vs baseline: 1.2097x; 1.0015x over previous
//
#include <hip/hip_runtime.h>
#include <hip/hip_fp16.h>

#define N_NODES 50000
#define N_ENT   100000
#define N_REL   16
#define DIM     128
#define E_EDGES 600000
#define NQ      8192
#define PATH_DIM 5
#define NK      (N_NODES * N_REL)        /* 800000 (rel,dst) segments */
#define KTOT    (N_REL * DIM + DIM)      /* 2176 = 16 rel slots + self slot */
#define NBLK_SEG (NK / 256)              /* 3125 */

typedef __attribute__((ext_vector_type(8))) short short8;
typedef __attribute__((ext_vector_type(4))) float floatx4;

static __device__ __forceinline__ short f2bf(float x) {
  unsigned u = __builtin_bit_cast(unsigned, x);
  u = (u + 0x7FFFu + ((u >> 16) & 1u)) >> 16;   // RNE
  return (short)u;
}
static __device__ __forceinline__ float bf_lo(unsigned u) {
  return __builtin_bit_cast(float, u << 16);
}
static __device__ __forceinline__ float bf_hi(unsigned u) {
  return __builtin_bit_cast(float, u & 0xffff0000u);
}
static __device__ __forceinline__ unsigned pk2(float a, float b) {
  return (unsigned)(unsigned short)f2bf(a) | ((unsigned)(unsigned short)f2bf(b) << 16);
}

static __device__ __forceinline__ int wave_incl_scan(int x) {
  int lane = threadIdx.x & 63;
  #pragma unroll
  for (int off = 1; off < 64; off <<= 1) {
    int y = __shfl_up(x, off, 64);
    if (lane >= off) x += y;
  }
  return x;
}

// ---------- edge sort by (etype*N + dst): hist -> scan -> scatter ----------
__global__ void k_hist(const int* __restrict__ ei, const int* __restrict__ et,
                       int* __restrict__ hist) {
  int e = blockIdx.x * 256 + threadIdx.x;
  if (e >= E_EDGES) return;
  int key = et[e] * N_NODES + ei[E_EDGES + e];
  atomicAdd(&hist[key], 1);
}

__global__ void k_bsum(const int* __restrict__ hist, int* __restrict__ bsum) {
  int t = threadIdx.x;
  int v = hist[blockIdx.x * 256 + t];
  #pragma unroll
  for (int off = 32; off; off >>= 1) v += __shfl_xor(v, off, 64);
  __shared__ int s4[4];
  if ((t & 63) == 0) s4[t >> 6] = v;
  __syncthreads();
  if (t == 0) bsum[blockIdx.x] = s4[0] + s4[1] + s4[2] + s4[3];
}

__global__ void k_bscan(int* __restrict__ bsum) {   // 1 block, 1024 threads, 3125 items
  int t = threadIdx.x;
  int v[4], loc[4], s = 0;
  #pragma unroll
  for (int i = 0; i < 4; i++) {
    int idx = t * 4 + i;
    v[i] = (idx < NBLK_SEG) ? bsum[idx] : 0;
    loc[i] = s; s += v[i];
  }
  int incl = wave_incl_scan(s);
  __shared__ int wsum[16];
  int wid = t >> 6, lane = t & 63;
  if (lane == 63) wsum[wid] = incl;
  __syncthreads();
  if (t < 16) {
    int x = wsum[t];
    #pragma unroll
    for (int off = 1; off < 16; off <<= 1) {
      int y = __shfl_up(x, off, 64);
      if (t >= off) x += y;
    }
    wsum[t] = x;
  }
  __syncthreads();
  int wexcl = wid ? wsum[wid - 1] : 0;
  int texcl = wexcl + incl - s;
  #pragma unroll
  for (int i = 0; i < 4; i++) {
    int idx = t * 4 + i;
    if (idx < NBLK_SEG) bsum[idx] = texcl + loc[i];
  }
}

__global__ void k_offsets(const int* __restrict__ hist, const int* __restrict__ bsum,
                          int* __restrict__ offs, int* __restrict__ cursor) {
  int t = threadIdx.x;
  int g = blockIdx.x * 256 + t;
  int v = hist[g];
  int incl = wave_incl_scan(v);
  __shared__ int wsum[4];
  int wid = t >> 6, lane = t & 63;
  if (lane == 63) wsum[wid] = incl;
  __syncthreads();
  int wexcl = 0;
  for (int i = 0; i < wid; i++) wexcl += wsum[i];
  int off = bsum[blockIdx.x] + wexcl + incl - v;
  offs[g] = off;
  cursor[g] = off;
  if (g == NK - 1) offs[NK] = off + v;
}

// writes epck: .x = src idx, .y = dst 16b | fp16(1/cnt) 16b
__global__ void k_scatter(const int* __restrict__ ei, const int* __restrict__ et,
                          const int* __restrict__ hist, int* __restrict__ cursor,
                          uint2* __restrict__ epck) {
  int e = blockIdx.x * 256 + threadIdx.x;
  if (e >= E_EDGES) return;
  int src = ei[e];
  int dst = ei[E_EDGES + e];
  int key = et[e] * N_NODES + dst;
  int pos = atomicAdd(&cursor[key], 1);
  int cnt = hist[key];
  __half hw = __float2half(1.0f / (float)cnt);
  uint2 rec;
  rec.x = (unsigned)src;
  rec.y = (unsigned)dst | ((unsigned)__half_as_ushort(hw) << 16);
  epck[pos] = rec;
}

// ---------- h0 gather (fp32 emb -> bf16 h) ----------
__global__ void k_h0(const int* __restrict__ nid, const float* __restrict__ emb,
                     unsigned* __restrict__ h) {
  int g = blockIdx.x * 256 + threadIdx.x;     // over N*32
  int n = g >> 5;
  int q = g & 31;
  float4 v = *(const float4*)(emb + (size_t)nid[n] * DIM + q * 4);
  uint2 pk;
  pk.x = pk2(v.x, v.y);
  pk.y = pk2(v.z, v.w);
  *(uint2*)(h + (size_t)n * 64 + q * 2) = pk;
}

// ---------- W_cat bf16, layout [layer][n=out 128][k=2176 (16 rel slots | self)] ----------
__global__ void k_wcat(const float* __restrict__ wrel, const float* __restrict__ wself,
                       short* __restrict__ wcat) {
  int g = blockIdx.x * 256 + threadIdx.x;
  if (g >= 2 * DIM * KTOT) return;
  int l = g / (DIM * KTOT);
  int rem = g - l * DIM * KTOT;
  int n = rem / KTOT;
  int k = rem - n * KTOT;
  float v;
  if (k < N_REL * DIM) {
    int r = k >> 7, d = k & 127;
    v = wrel[(((size_t)l * N_REL + r) * DIM + d) * DIM + n];
  } else {
    int d = k - N_REL * DIM;
    v = wself[((size_t)l * DIM + d) * DIM + n];
  }
  wcat[g] = f2bf(v);
}

// ---------- fused layer, K-split in 2 groups: edge-stream mean -> LDS A -> MFMA ----------
// grid (RB, 2). Group g handles rel slots 8g..8g+7 (g=1 also self slot) and writes
// fp32 partial C to cpart[g]. Block = 4 waves x 16 rows, no barriers.
__global__ __launch_bounds__(256) void k_layer(const unsigned* __restrict__ h,
                                               const int* __restrict__ offs,
                                               const uint2* __restrict__ epck,
                                               const short* __restrict__ wb,
                                               float* __restrict__ cpart) {
  __shared__ short As[4][4][16][40];   // per wave, 4 k-chunks of [16 rows][40 shorts]
  int t = threadIdx.x;
  int w = t >> 6, lane = t & 63;
  int quad = lane >> 4, rA = lane & 15;
  int row0 = blockIdx.x * 64 + w * 16;
  int grp = blockIdx.y;
  int rbase = grp * 8;

  // slot boundaries in registers: lane (2*rr+which) holds offs[(rbase+rr)*N + row0+16*which]
  int bnd = 0;
  if (lane < 16) {
    int r = rbase + (lane >> 1), which = lane & 1;
    int rowc = row0 + which * 16;
    if (rowc > N_NODES) rowc = N_NODES;
    bnd = offs[r * N_NODES + rowc];
  }

  floatx4 acc[8];
  #pragma unroll
  for (int b = 0; b < 8; b++) acc[b] = (floatx4)0.f;

  int wchunk = lane >> 4;           // which 32-col k-chunk this lane's 2 cols fall in
  int wcol   = (lane * 2) & 31;     // col within chunk

  const int nslot = 8 + grp;        // group 1 also does the self slot (rr==8)
  #pragma unroll 1
  for (int rr = 0; rr < nslot; rr++) {
    if (rr < 8) {
      int b0   = __shfl(bnd, rr * 2);
      int bend = __shfl(bnd, rr * 2 + 1);
      // pre-clear the 16 A rows (covers empty segments)
      #pragma unroll
      for (int i = 0; i < 16; i++)
        *(unsigned*)&As[w][wchunk][i][wcol] = 0u;
      float a0 = 0.f, a1 = 0.f;
      int cur = -1;
      #pragma unroll 1
      for (int chunk = b0; chunk < bend; chunk += 64) {
        int clampp = min(chunk + lane, bend - 1);
        uint2 myrec = epck[clampp];
        #pragma unroll 1
        for (int g = 0; g < 4; g++) {
          int jb = chunk + g * 16;
          if (jb >= bend) break;
          int      sj[16];
          unsigned pj[16];
          #pragma unroll
          for (int j = 0; j < 16; j++) {
            sj[j] = __shfl((int)myrec.x, g * 16 + j);
            pj[j] = __shfl(myrec.y, g * 16 + j);
          }
          unsigned u[16];
          #pragma unroll
          for (int j = 0; j < 16; j++)
            u[j] = h[(size_t)sj[j] * 64 + lane];   // unconditional (clamped addr)
          #pragma unroll
          for (int j = 0; j < 16; j++) {
            int p = jb + j;
            if (p < bend) {                        // wave-uniform
              int dstj = (int)(pj[j] & 0xffffu);
              if (dstj != cur) {                   // wave-uniform
                if (cur >= 0)
                  *(unsigned*)&As[w][wchunk][cur - row0][wcol] = pk2(a0, a1);
                cur = dstj; a0 = 0.f; a1 = 0.f;
              }
              float wgt = __half2float(__ushort_as_half((unsigned short)(pj[j] >> 16)));
              a0 += bf_lo(u[j]) * wgt;
              a1 += bf_hi(u[j]) * wgt;
            }
          }
        }
      }
      if (cur >= 0)
        *(unsigned*)&As[w][wchunk][cur - row0][wcol] = pk2(a0, a1);
    } else {
      // self slot: copy own h rows
      #pragma unroll 4
      for (int i = 0; i < 16; i++) {
        int row = row0 + i;
        unsigned uu = (row < N_NODES) ? h[(size_t)row * 64 + lane] : 0u;
        *(unsigned*)&As[w][wchunk][i][wcol] = uu;
      }
    }
    // ---- MFMA: 4 k-steps over this 128-col slot ----
    int rglob = (rr < 8) ? (rbase + rr) : 16;
    const short* wbr = wb + rglob * 128;
    #pragma unroll
    for (int ks = 0; ks < 4; ks++) {
      short8 a0v = *(const short8*)&As[w][ks][rA][quad * 8];
      #pragma unroll
      for (int nt = 0; nt < 8; nt++) {
        short8 b = *(const short8*)(wbr + (size_t)(nt * 16 + rA) * KTOT + ks * 32 + quad * 8);
        acc[nt] = __builtin_amdgcn_mfma_f32_16x16x32_bf16(a0v, b, acc[nt], 0, 0, 0);
      }
    }
  }
  // ---- epilogue: fp32 partial store. C: row=(lane>>4)*4+reg, col=lane&15 ----
  float* cp = cpart + (size_t)grp * N_NODES * DIM;
  #pragma unroll
  for (int nt = 0; nt < 8; nt++)
    #pragma unroll
    for (int j = 0; j < 4; j++) {
      int row = row0 + quad * 4 + j;
      int col = nt * 16 + rA;
      if (row < N_NODES) cp[(size_t)row * DIM + col] = acc[nt][j];
    }
}

// ---------- combine partials: h = relu(p0 + p1) in bf16 ----------
__global__ void k_combine(const float* __restrict__ cpart, unsigned* __restrict__ h) {
  int g = blockIdx.x * 256 + threadIdx.x;     // over N*32
  int n = g >> 5;
  int q = g & 31;
  size_t o = (size_t)n * DIM + q * 4;
  float4 a = *(const float4*)(cpart + o);
  float4 b = *(const float4*)(cpart + (size_t)N_NODES * DIM + o);
  float4 s;
  s.x = fmaxf(a.x + b.x, 0.f); s.y = fmaxf(a.y + b.y, 0.f);
  s.z = fmaxf(a.z + b.z, 0.f); s.w = fmaxf(a.w + b.w, 0.f);
  uint2 pk;
  pk.x = pk2(s.x, s.y);
  pk.y = pk2(s.z, s.w);
  *(uint2*)(h + (size_t)n * 64 + q * 2) = pk;
}

// ---------- scoring (bf16 h) ----------
__global__ void k_score(const unsigned* __restrict__ h, const int* __restrict__ heads,
                        const int* __restrict__ rels, const int* __restrict__ tails,
                        const float* __restrict__ rel_emb, const float* __restrict__ path_feat,
                        const int* __restrict__ task_idx, const float* __restrict__ delta_w,
                        const float* __restrict__ lambda_logit, const float* __restrict__ rule_init,
                        float* __restrict__ out) {
  int q = (blockIdx.x * 256 + threadIdx.x) >> 6;
  int lane = threadIdx.x & 63;
  int hd = heads[q], tl = tails[q], rl = rels[q];
  unsigned ua = h[(size_t)hd * 64 + lane];
  unsigned uc = h[(size_t)tl * 64 + lane];
  float2 r = *(const float2*)(rel_emb + (size_t)rl * DIM + lane * 2);
  float s = bf_lo(ua) * r.x * bf_lo(uc) + bf_hi(ua) * r.y * bf_hi(uc);
  #pragma unroll
  for (int off = 32; off; off >>= 1) s += __shfl_xor(s, off, 64);
  if (lane == 0) {
    int task = task_idx[0];
    float sp = 0.f;
    #pragma unroll
    for (int p = 0; p < PATH_DIM; p++)
      sp += path_feat[q * PATH_DIM + p] *
            (rule_init[task * PATH_DIM + p] + delta_w[task * PATH_DIM + p]);
    float lam = 1.f / (1.f + __expf(-lambda_logit[task]));
    out[q] = lam * s + (1.f - lam) * sp;
  }
}

extern "C" void kernel_launch(void* const* d_in, const int* in_sizes, int n_in,
                              void* d_out, int out_size, void* d_ws, size_t ws_size,
                              hipStream_t stream) {
  const int*   node_ids   = (const int*)d_in[0];
  const int*   edge_index = (const int*)d_in[1];
  const int*   edge_type  = (const int*)d_in[2];
  const int*   heads      = (const int*)d_in[3];
  const int*   rels       = (const int*)d_in[4];
  const int*   tails      = (const int*)d_in[5];
  const float* path_feat  = (const float*)d_in[6];
  const int*   task_idx   = (const int*)d_in[7];
  const float* entity_emb = (const float*)d_in[8];
  const float* rel_emb    = (const float*)d_in[9];
  const float* W_self     = (const float*)d_in[10];
  const float* W_rel      = (const float*)d_in[11];
  const float* delta_w    = (const float*)d_in[12];
  const float* lambda_lg  = (const float*)d_in[13];
  const float* rule_init  = (const float*)d_in[14];

  char* ws = (char*)d_ws;
  size_t off = 0;
  auto alloc = [&](size_t bytes) -> void* {
    void* p = ws + off;
    off = (off + bytes + 255) & ~(size_t)255;
    return p;
  };
  // persistent: ~34.8 MB
  unsigned* h_a   = (unsigned*)alloc((size_t)N_NODES * DIM * 2);
  unsigned* h_b   = (unsigned*)alloc((size_t)N_NODES * DIM * 2);
  short*    wcat  = (short*)alloc((size_t)2 * DIM * KTOT * 2);
  int*      offs  = (int*)alloc((size_t)(NK + 1) * 4);
  uint2*    epck  = (uint2*)alloc((size_t)E_EDGES * 8);
  // cpart (2 x 25.6 MB fp32) — total ~86 MB, fits the known-safe <90 MB budget.
  float*    cpart = (float*)alloc((size_t)2 * N_NODES * DIM * 4);
  // hist/cursor/bsum are dead after the sort -> overlap into cpart region
  int* hist   = (int*)cpart;
  int* cursor = hist + (NK + 1);
  int* bsum   = cursor + NK;

  hipMemsetAsync(hist, 0, (size_t)(NK + 1) * 4, stream);
  int eb = (E_EDGES + 255) / 256;
  k_hist<<<eb, 256, 0, stream>>>(edge_index, edge_type, hist);
  k_bsum<<<NBLK_SEG, 256, 0, stream>>>(hist, bsum);
  k_bscan<<<1, 1024, 0, stream>>>(bsum);
  k_offsets<<<NBLK_SEG, 256, 0, stream>>>(hist, bsum, offs, cursor);
  k_scatter<<<eb, 256, 0, stream>>>(edge_index, edge_type, hist, cursor, epck);
  k_h0<<<(N_NODES * 32) / 256, 256, 0, stream>>>(node_ids, entity_emb, h_a);
  k_wcat<<<(2 * DIM * KTOT + 255) / 256, 256, 0, stream>>>(W_rel, W_self, wcat);

  const int RB = (N_NODES + 63) / 64;
  dim3 lgrid(RB, 2);
  const int cblocks = (N_NODES * 32) / 256;
  // layer 1: h_a -> cpart -> h_b
  k_layer<<<lgrid, 256, 0, stream>>>(h_a, offs, epck, wcat, cpart);
  k_combine<<<cblocks, 256, 0, stream>>>(cpart, h_b);
  // layer 2: h_b -> cpart -> h_a
  k_layer<<<lgrid, 256, 0, stream>>>(h_b, offs, epck, wcat + (size_t)DIM * KTOT, cpart);
  k_combine<<<cblocks, 256, 0, stream>>>(cpart, h_a);

  k_score<<<NQ / 4, 256, 0, stream>>>(h_a, heads, rels, tails, rel_emb, path_feat,
                                      task_idx, delta_w, lambda_lg, rule_init,
                                      (float*)d_out);
}